// Round 3
// baseline (210.322 us; speedup 1.0000x reference)
//
#include <hip/hip_runtime.h>

#define VOCAB 50000
#define EMBED 256
#define NB    16
#define NC    64
#define NS    512
#define UNK   1

#define CTILE 8               // c's per block
#define JT    16              // j tiles
#define JLEN  (NS / JT)       // 32 j's per tile
#define NBLOCKS (NB * (NC / CTILE) * JT)   // 2048

// Fused kernel. Grid = 2048 blocks x 256 thr = 8192 waves = 100% device capacity.
// Block (b, ct, jt): partial[jt][b*64+c0+i] = sum_{j in tile, q>0} <emb[src], emb[q]>.
// Last block to finish (device-scope counter) performs softmax+argmax+row copy.
__global__ __launch_bounds__(256) void scores_kernel(
    const int* __restrict__ src, const int* __restrict__ q,
    const float* __restrict__ emb, float* __restrict__ partial,
    unsigned int* __restrict__ done, float* __restrict__ out)
{
    const int x  = blockIdx.x;
    const int jt = x & (JT - 1);
    const int ct = (x >> 4) & (NC / CTILE - 1);
    const int b  = x >> 7;
    const int c0 = ct * CTILE;
    const int j0 = jt * JLEN;

    const int tid  = threadIdx.x;
    const int wave = tid >> 6;
    const int lane = tid & 63;          // float4 index into 256-float row

    const float4* __restrict__ emb4 = (const float4*)emb;
    const int* __restrict__ qrow = q + (size_t)b * NS;
    const int* __restrict__ srow = src + ((size_t)b * NC + c0) * NS;

    float acc[CTILE];
#pragma unroll
    for (int i = 0; i < CTILE; i++) acc[i] = 0.f;

    for (int j = j0 + wave; j < j0 + JLEN; j += 4) {
        const int qv = qrow[j];
        if (qv > 0) {                                   // wave-uniform
            const int qid = (qv >= VOCAB) ? UNK : qv;
            const float4 eq = emb4[(size_t)qid * (EMBED / 4) + lane];

            int sid[CTILE];
#pragma unroll
            for (int i = 0; i < CTILE; i++) {
                const int sv = srow[(size_t)i * NS + j];
                sid[i] = (sv >= VOCAB) ? UNK : sv;
            }
            float4 a[CTILE];
#pragma unroll
            for (int i = 0; i < CTILE; i++)
                a[i] = emb4[(size_t)sid[i] * (EMBED / 4) + lane];
#pragma unroll
            for (int i = 0; i < CTILE; i++)
                acc[i] += a[i].x * eq.x + a[i].y * eq.y + a[i].z * eq.z + a[i].w * eq.w;
        }
    }

#pragma unroll
    for (int off = 32; off > 0; off >>= 1)
#pragma unroll
        for (int i = 0; i < CTILE; i++)
            acc[i] += __shfl_down(acc[i], off, 64);

    __shared__ float red[4][CTILE];
    if (lane == 0)
#pragma unroll
        for (int i = 0; i < CTILE; i++) red[wave][i] = acc[i];
    __syncthreads();

    if (tid < CTILE) {
        const float s = red[0][tid] + red[1][tid] + red[2][tid] + red[3][tid];
        partial[(size_t)jt * (NB * NC) + b * NC + c0 + tid] = s;
    }

    // ---- last-block-done: only one block proceeds to finalize ----
    __shared__ int is_last;
    __syncthreads();                       // partial stores issued by all threads
    if (tid == 0) {
        __threadfence();                   // agent release: write back L2
        is_last = (atomicAdd(done, 1u) == NBLOCKS - 1u) ? 1 : 0;
    }
    __syncthreads();
    if (!is_last) return;
    __threadfence();                       // agent acquire: invalidate stale L2

    // ---- finalize: 4 waves, wave w handles b = 4w .. 4w+3; lane = c ----
    const int w = wave;
#pragma unroll
    for (int bi = 0; bi < 4; bi++) {
        const int bb = w * 4 + bi;

        float s = 0.f;
#pragma unroll
        for (int t = 0; t < JT; t++)
            s += partial[(size_t)t * (NB * NC) + bb * NC + lane];

        float m = s;
#pragma unroll
        for (int off = 32; off > 0; off >>= 1)
            m = fmaxf(m, __shfl_xor(m, off, 64));

        const float e = expf(s - m);
        float sum = e;
#pragma unroll
        for (int off = 32; off > 0; off >>= 1)
            sum += __shfl_xor(sum, off, 64);

        out[NB * NS + bb * NC + lane] = e / sum;   // sims after 8192 out_sources

        const unsigned long long ballot = __ballot(s == m);
        const int top = __ffsll(ballot) - 1;        // first-occurrence argmax

        const int* __restrict__ trow = src + ((size_t)bb * NC + top) * NS;
#pragma unroll
        for (int j = lane; j < NS; j += 64)
            out[bb * NS + j] = (float)trow[j];
    }
}

extern "C" void kernel_launch(void* const* d_in, const int* in_sizes, int n_in,
                              void* d_out, int out_size, void* d_ws, size_t ws_size,
                              hipStream_t stream) {
    const int*   src = (const int*)d_in[0];    // [NB*NC, NS] int32
    const int*   q   = (const int*)d_in[1];    // [NB, NS] int32
    const float* emb = (const float*)d_in[3];  // [VOCAB, EMBED] f32

    float* out     = (float*)d_out;            // 8192 out_sources + 1024 sims (f32)
    float* partial = (float*)d_ws;             // [JT][NB*NC] = 32768 floats (128 KB)
    unsigned int* done = (unsigned int*)((char*)d_ws + (size_t)JT * NB * NC * sizeof(float));

    hipMemsetAsync(done, 0, sizeof(unsigned int), stream);   // ws is poisoned 0xAA
    scores_kernel<<<NBLOCKS, 256, 0, stream>>>(src, q, emb, partial, done, out);
}

// Round 5
// 150.943 us; speedup vs baseline: 1.3934x; 1.3934x over previous
//
#include <hip/hip_runtime.h>

#define VOCAB 50000
#define EMBED 256
#define NB    16
#define NC    64
#define NS    512
#define UNK   1

#define CTILE 8              // c's per block
#define JT    8              // j tiles
#define JLEN  (NS / JT)      // 64 j's per tile

// Partial scores: grid = NB * (NC/CTILE) * JT = 1024 blocks, 256 thr.
// Ids for the whole (8 c x 64 j) tile are staged in LDS (coalesced), the
// query-prefix length within the tile comes from one ballot, and the main
// loop is branchless so the compiler can pipeline gather iterations.
__global__ __launch_bounds__(256) void scores_kernel(
    const int* __restrict__ src, const int* __restrict__ q,
    const float* __restrict__ emb, float* __restrict__ partial)
{
    const int x  = blockIdx.x;
    const int jt = x & (JT - 1);
    const int ct = (x >> 3) & (NC / CTILE - 1);
    const int b  = x >> 6;
    const int c0 = ct * CTILE;
    const int j0 = jt * JLEN;

    const int tid  = threadIdx.x;
    const int wave = tid >> 6;
    const int lane = tid & 63;          // float4 index into 256-float row

    const float4* __restrict__ emb4 = (const float4*)emb;
    const int* __restrict__ qrow = q + (size_t)b * NS;
    const int* __restrict__ srow = src + ((size_t)b * NC + c0) * NS;

    __shared__ int sids[CTILE][JLEN];   // 2 KB, clamped source ids
    __shared__ int qids[JLEN];          // clamped query ids
    __shared__ int nnz_sh;              // # valid j's in this tile (prefix)

    // wave 0: stage query ids + tile-local prefix length via ballot
    if (tid < 64) {
        const int qv = qrow[j0 + tid];
        qids[tid] = (qv >= VOCAB) ? UNK : qv;
        const unsigned long long bal = __ballot(qv > 0);
        if (tid == 0) nnz_sh = __popcll(bal);
    }
    // all 256 threads: stage 512 source ids (2 per thread, coalesced)
#pragma unroll
    for (int k = 0; k < 2; k++) {
        const int idx = tid + k * 256;
        const int i   = idx >> 6;       // c within tile
        const int j   = idx & 63;
        const int sv  = srow[(size_t)i * NS + j0 + j];
        sids[i][j] = (sv >= VOCAB) ? UNK : sv;
    }
    __syncthreads();

    const int nnz = nnz_sh;             // contiguous prefix => trip count

    float acc[CTILE];
#pragma unroll
    for (int i = 0; i < CTILE; i++) acc[i] = 0.f;

#pragma unroll 2
    for (int j = wave; j < nnz; j += 4) {
        const int qid = qids[j];                         // LDS broadcast
        const float4 eq = emb4[(size_t)qid * (EMBED / 4) + lane];
        float4 a[CTILE];
#pragma unroll
        for (int i = 0; i < CTILE; i++)
            a[i] = emb4[(size_t)sids[i][j] * (EMBED / 4) + lane];
#pragma unroll
        for (int i = 0; i < CTILE; i++)
            acc[i] += a[i].x * eq.x + a[i].y * eq.y + a[i].z * eq.z + a[i].w * eq.w;
    }

    // wave reduce all 8 accumulators
#pragma unroll
    for (int off = 32; off > 0; off >>= 1)
#pragma unroll
        for (int i = 0; i < CTILE; i++)
            acc[i] += __shfl_down(acc[i], off, 64);

    __shared__ float red[4][CTILE];
    if (lane == 0)
#pragma unroll
        for (int i = 0; i < CTILE; i++) red[wave][i] = acc[i];
    __syncthreads();

    if (tid < CTILE) {
        const float s = red[0][tid] + red[1][tid] + red[2][tid] + red[3][tid];
        partial[(size_t)jt * (NB * NC) + b * NC + c0 + tid] = s;
    }
}

// One block per b, 256 threads. Wave 0: sum JT partials -> softmax -> sims,
// first-occurrence argmax. Then all 256 threads copy the winning source row.
__global__ __launch_bounds__(256) void finalize_kernel(
    const float* __restrict__ partial, const int* __restrict__ src,
    float* __restrict__ out)
{
    const int b   = blockIdx.x;
    const int tid = threadIdx.x;

    __shared__ int top_sh;

    if (tid < 64) {
        const int c = tid;
        float s = 0.f;
#pragma unroll
        for (int jt = 0; jt < JT; jt++)
            s += partial[(size_t)jt * (NB * NC) + b * NC + c];

        float m = s;
#pragma unroll
        for (int off = 32; off > 0; off >>= 1)
            m = fmaxf(m, __shfl_xor(m, off, 64));

        const float e = expf(s - m);
        float sum = e;
#pragma unroll
        for (int off = 32; off > 0; off >>= 1)
            sum += __shfl_xor(sum, off, 64);

        out[NB * NS + b * NC + c] = e / sum;     // sims after 8192 out_sources

        const unsigned long long ballot = __ballot(s == m);
        if (tid == 0) top_sh = __ffsll(ballot) - 1;
    }
    __syncthreads();

    const int top = top_sh;
    const int* __restrict__ srow = src + ((size_t)b * NC + top) * NS;
#pragma unroll
    for (int j = tid; j < NS; j += 256)
        out[b * NS + j] = (float)srow[j];
}

extern "C" void kernel_launch(void* const* d_in, const int* in_sizes, int n_in,
                              void* d_out, int out_size, void* d_ws, size_t ws_size,
                              hipStream_t stream) {
    const int*   src = (const int*)d_in[0];    // [NB*NC, NS] int32
    const int*   q   = (const int*)d_in[1];    // [NB, NS] int32
    const float* emb = (const float*)d_in[3];  // [VOCAB, EMBED] f32

    float* out     = (float*)d_out;            // 8192 out_sources + 1024 sims (f32)
    float* partial = (float*)d_ws;             // [JT][NB*NC] = 8192 floats

    scores_kernel<<<NB * (NC / CTILE) * JT, 256, 0, stream>>>(src, q, emb, partial);
    finalize_kernel<<<NB, 256, 0, stream>>>(partial, src, out);
}

// Round 6
// 132.768 us; speedup vs baseline: 1.5841x; 1.1369x over previous
//
#include <hip/hip_runtime.h>

#define VOCAB 50000
#define EMBED 256
#define NB    16
#define NC    64
#define NS    512
#define UNK   1

// ---- bf16 fast path geometry ----
#define CTILE 8               // c's per block
#define JT    16              // j tiles
#define JLEN  (NS / JT)       // 32 j's per tile
#define BF_TABLE_BYTES ((size_t)VOCAB * EMBED * 2)          // 25,600,000
#define PARTIAL_ELEMS  (JT * NB * NC)                       // 16384

__device__ __forceinline__ unsigned short f2bf_rne(float f) {
    unsigned int u = __float_as_uint(f);
    u = (u + 0x7fffu + ((u >> 16) & 1u)) >> 16;             // round-nearest-even
    return (unsigned short)u;
}

// Stream-convert emb f32 -> bf16 table in ws. 1.6M threads x 8 elems.
__global__ __launch_bounds__(256) void convert_kernel(
    const float* __restrict__ emb, unsigned int* __restrict__ bf)
{
    const size_t t = (size_t)blockIdx.x * 256 + threadIdx.x;
    const float4* __restrict__ e4 = (const float4*)emb;
    const float4 a = e4[t * 2];
    const float4 b = e4[t * 2 + 1];
    uint4 r;
    r.x = (unsigned int)f2bf_rne(a.x) | ((unsigned int)f2bf_rne(a.y) << 16);
    r.y = (unsigned int)f2bf_rne(a.z) | ((unsigned int)f2bf_rne(a.w) << 16);
    r.z = (unsigned int)f2bf_rne(b.x) | ((unsigned int)f2bf_rne(b.y) << 16);
    r.w = (unsigned int)f2bf_rne(b.z) | ((unsigned int)f2bf_rne(b.w) << 16);
    ((uint4*)bf)[t] = r;
}

// Gather-bound scores, bf16 source rows (512 B each), f32 query rows staged
// in LDS once per block. Grid = NB * (NC/CTILE) * JT = 2048 blocks, 256 thr.
__global__ __launch_bounds__(256) void scores_bf_kernel(
    const int* __restrict__ src, const int* __restrict__ q,
    const float* __restrict__ emb, const unsigned int* __restrict__ bf,
    float* __restrict__ partial)
{
    const int x  = blockIdx.x;
    const int jt = x & (JT - 1);
    const int ct = (x >> 4) & (NC / CTILE - 1);
    const int b  = x >> 7;
    const int c0 = ct * CTILE;
    const int j0 = jt * JLEN;

    const int tid  = threadIdx.x;
    const int wave = tid >> 6;
    const int lane = tid & 63;          // covers elements [4*lane, 4*lane+3]

    const float4* __restrict__ emb4 = (const float4*)emb;
    const uint2*  __restrict__ bfe  = (const uint2*)bf;       // 64 uint2 per row
    const int* __restrict__ qrow = q + (size_t)b * NS;
    const int* __restrict__ srow = src + ((size_t)b * NC + c0) * NS;

    __shared__ float qt[JLEN][EMBED];   // 32 KB: masked-prefix query rows, f32
    __shared__ int   sids[CTILE][JLEN];
    __shared__ int   qids[JLEN];
    __shared__ int   nnz_sh;

    if (tid < 64) {                                  // wave 0
        const int qv = (tid < JLEN) ? qrow[j0 + tid] : 0;
        if (tid < JLEN) qids[tid] = (qv >= VOCAB) ? UNK : qv;
        const unsigned long long bal = __ballot(qv > 0);
        if (tid == 0) nnz_sh = __popcll(bal);        // contiguous prefix in tile
    }
    {   // 256 ids, one per thread, coalesced
        const int i = tid >> 5, j = tid & 31;
        const int sv = srow[(size_t)i * NS + j0 + j];
        sids[i][j] = (sv >= VOCAB) ? UNK : sv;
    }
    __syncthreads();

    const int nnz = nnz_sh;

    // stage f32 query rows for valid j's (wave w -> rows w, w+4, ...)
    float4* qt4 = (float4*)qt;
    for (int r = wave; r < nnz; r += 4)
        qt4[r * 64 + lane] = emb4[(size_t)qids[r] * (EMBED / 4) + lane];
    __syncthreads();

    float acc[CTILE];
#pragma unroll
    for (int i = 0; i < CTILE; i++) acc[i] = 0.f;

#pragma unroll 2
    for (int j = wave; j < nnz; j += 4) {
        const float4 qv = qt4[j * 64 + lane];        // ds_read_b128
        uint2 a[CTILE];
#pragma unroll
        for (int i = 0; i < CTILE; i++)
            a[i] = bfe[(size_t)sids[i][j] * 64 + lane];   // 8 B/lane bf16 gather
#pragma unroll
        for (int i = 0; i < CTILE; i++) {
            const float f0 = __uint_as_float(a[i].x << 16);
            const float f1 = __uint_as_float(a[i].x & 0xffff0000u);
            const float f2 = __uint_as_float(a[i].y << 16);
            const float f3 = __uint_as_float(a[i].y & 0xffff0000u);
            acc[i] += f0 * qv.x + f1 * qv.y + f2 * qv.z + f3 * qv.w;
        }
    }

#pragma unroll
    for (int off = 32; off > 0; off >>= 1)
#pragma unroll
        for (int i = 0; i < CTILE; i++)
            acc[i] += __shfl_down(acc[i], off, 64);

    __shared__ float red[4][CTILE];
    if (lane == 0)
#pragma unroll
        for (int i = 0; i < CTILE; i++) red[wave][i] = acc[i];
    __syncthreads();

    if (tid < CTILE) {
        const float s = red[0][tid] + red[1][tid] + red[2][tid] + red[3][tid];
        partial[(size_t)jt * (NB * NC) + b * NC + c0 + tid] = s;
    }
}

// ---- f32 fallback (proven R5 path), JT=8/JLEN=64 ----
__global__ __launch_bounds__(256) void scores_f32_kernel(
    const int* __restrict__ src, const int* __restrict__ q,
    const float* __restrict__ emb, float* __restrict__ partial)
{
    const int x  = blockIdx.x;
    const int jt = x & 7;
    const int ct = (x >> 3) & 7;
    const int b  = x >> 6;
    const int c0 = ct * CTILE;
    const int j0 = jt * 64;

    const int tid = threadIdx.x, wave = tid >> 6, lane = tid & 63;
    const float4* __restrict__ emb4 = (const float4*)emb;
    const int* __restrict__ qrow = q + (size_t)b * NS;
    const int* __restrict__ srow = src + ((size_t)b * NC + c0) * NS;

    float acc[CTILE];
#pragma unroll
    for (int i = 0; i < CTILE; i++) acc[i] = 0.f;

    for (int j = j0 + wave; j < j0 + 64; j += 4) {
        const int qv = qrow[j];
        if (qv > 0) {
            const int qid = (qv >= VOCAB) ? UNK : qv;
            const float4 eq = emb4[(size_t)qid * (EMBED / 4) + lane];
            float4 a[CTILE];
#pragma unroll
            for (int i = 0; i < CTILE; i++) {
                const int sv = srow[(size_t)i * NS + j];
                a[i] = emb4[(size_t)((sv >= VOCAB) ? UNK : sv) * (EMBED / 4) + lane];
            }
#pragma unroll
            for (int i = 0; i < CTILE; i++)
                acc[i] += a[i].x * eq.x + a[i].y * eq.y + a[i].z * eq.z + a[i].w * eq.w;
        }
    }
#pragma unroll
    for (int off = 32; off > 0; off >>= 1)
#pragma unroll
        for (int i = 0; i < CTILE; i++)
            acc[i] += __shfl_down(acc[i], off, 64);

    __shared__ float red[4][CTILE];
    if (lane == 0)
#pragma unroll
        for (int i = 0; i < CTILE; i++) red[wave][i] = acc[i];
    __syncthreads();
    if (tid < CTILE)
        partial[(size_t)jt * (NB * NC) + b * NC + c0 + tid] =
            red[0][tid] + red[1][tid] + red[2][tid] + red[3][tid];
}

// One block per b. Wave 0: sum jtn partials -> softmax -> sims + argmax;
// then all 256 threads copy the winning source row as f32.
__global__ __launch_bounds__(256) void finalize_kernel(
    const float* __restrict__ partial, const int* __restrict__ src,
    float* __restrict__ out, int jtn)
{
    const int b = blockIdx.x, tid = threadIdx.x;
    __shared__ int top_sh;

    if (tid < 64) {
        float s = 0.f;
        for (int t = 0; t < jtn; t++)
            s += partial[(size_t)t * (NB * NC) + b * NC + tid];

        float m = s;
#pragma unroll
        for (int off = 32; off > 0; off >>= 1)
            m = fmaxf(m, __shfl_xor(m, off, 64));
        const float e = expf(s - m);
        float sum = e;
#pragma unroll
        for (int off = 32; off > 0; off >>= 1)
            sum += __shfl_xor(sum, off, 64);

        out[NB * NS + b * NC + tid] = e / sum;       // sims after 8192 ids

        const unsigned long long ballot = __ballot(s == m);
        if (tid == 0) top_sh = __ffsll(ballot) - 1;  // first occurrence
    }
    __syncthreads();

    const int top = top_sh;
    const int* __restrict__ srow = src + ((size_t)b * NC + top) * NS;
    for (int j = tid; j < NS; j += 256)
        out[b * NS + j] = (float)srow[j];
}

extern "C" void kernel_launch(void* const* d_in, const int* in_sizes, int n_in,
                              void* d_out, int out_size, void* d_ws, size_t ws_size,
                              hipStream_t stream) {
    const int*   src = (const int*)d_in[0];    // [NB*NC, NS] int32
    const int*   q   = (const int*)d_in[1];    // [NB, NS] int32
    const float* emb = (const float*)d_in[3];  // [VOCAB, EMBED] f32
    float* out = (float*)d_out;                // 8192 out_sources + 1024 sims (f32)

    if (ws_size >= BF_TABLE_BYTES + PARTIAL_ELEMS * sizeof(float)) {
        unsigned int* bf = (unsigned int*)d_ws;
        float* partial = (float*)((char*)d_ws + BF_TABLE_BYTES);
        convert_kernel<<<VOCAB * EMBED / 2048, 256, 0, stream>>>(emb, bf);
        scores_bf_kernel<<<NB * (NC / CTILE) * JT, 256, 0, stream>>>(src, q, emb, bf, partial);
        finalize_kernel<<<NB, 256, 0, stream>>>(partial, src, out, JT);
    } else {
        float* partial = (float*)d_ws;         // 8192 floats
        scores_f32_kernel<<<NB * 8 * 8, 256, 0, stream>>>(src, q, emb, partial);
        finalize_kernel<<<NB, 256, 0, stream>>>(partial, src, out, 8);
    }
}

// Round 7
// 129.855 us; speedup vs baseline: 1.6197x; 1.0224x over previous
//
#include <hip/hip_runtime.h>

#define VOCAB 50000
#define EMBED 256
#define NB    16
#define NC    64
#define NS    512
#define UNK   1

// ---- bf16 fast path geometry ----
#define CTILE 16              // c's per block (R7: 8 -> 16, halves query-staging redundancy)
#define JT    16              // j tiles
#define JLEN  (NS / JT)       // 32 j's per tile
#define BF_TABLE_BYTES ((size_t)VOCAB * EMBED * 2)          // 25,600,000
#define PARTIAL_ELEMS  (JT * NB * NC)                       // 16384

__device__ __forceinline__ unsigned short f2bf_rne(float f) {
    unsigned int u = __float_as_uint(f);
    u = (u + 0x7fffu + ((u >> 16) & 1u)) >> 16;             // round-nearest-even
    return (unsigned short)u;
}

// Stream-convert emb f32 -> bf16 table in ws. 400k threads x 8 elems.
__global__ __launch_bounds__(256) void convert_kernel(
    const float* __restrict__ emb, unsigned int* __restrict__ bf)
{
    const size_t t = (size_t)blockIdx.x * 256 + threadIdx.x;
    const float4* __restrict__ e4 = (const float4*)emb;
    const float4 a = e4[t * 2];
    const float4 b = e4[t * 2 + 1];
    uint4 r;
    r.x = (unsigned int)f2bf_rne(a.x) | ((unsigned int)f2bf_rne(a.y) << 16);
    r.y = (unsigned int)f2bf_rne(a.z) | ((unsigned int)f2bf_rne(a.w) << 16);
    r.z = (unsigned int)f2bf_rne(b.x) | ((unsigned int)f2bf_rne(b.y) << 16);
    r.w = (unsigned int)f2bf_rne(b.z) | ((unsigned int)f2bf_rne(b.w) << 16);
    ((uint4*)bf)[t] = r;
}

// Gather-bound scores, bf16 source rows (512 B each), f32 query rows staged
// in LDS once per block. Grid = NB * (NC/CTILE) * JT = 1024 blocks, 256 thr.
__global__ __launch_bounds__(256) void scores_bf_kernel(
    const int* __restrict__ src, const int* __restrict__ q,
    const float* __restrict__ emb, const unsigned int* __restrict__ bf,
    float* __restrict__ partial)
{
    const int x  = blockIdx.x;
    const int jt = x & (JT - 1);
    const int ct = (x >> 4) & (NC / CTILE - 1);
    const int b  = x >> 6;
    const int c0 = ct * CTILE;
    const int j0 = jt * JLEN;

    const int tid  = threadIdx.x;
    const int wave = tid >> 6;
    const int lane = tid & 63;          // covers elements [4*lane, 4*lane+3]

    const float4* __restrict__ emb4 = (const float4*)emb;
    const uint2*  __restrict__ bfe  = (const uint2*)bf;       // 64 uint2 per row
    const int* __restrict__ qrow = q + (size_t)b * NS;
    const int* __restrict__ srow = src + ((size_t)b * NC + c0) * NS;

    __shared__ float qt[JLEN][EMBED];   // 32 KB: query rows for this j tile, f32
    __shared__ int   sids[CTILE][JLEN]; // 2 KB clamped source ids
    __shared__ int   qids[JLEN];
    __shared__ int   nnz_sh;

    if (tid < 64) {                                  // wave 0
        const int qv = (tid < JLEN) ? qrow[j0 + tid] : 0;
        if (tid < JLEN) qids[tid] = (qv >= VOCAB) ? UNK : qv;
        const unsigned long long bal = __ballot(qv > 0);
        if (tid == 0) nnz_sh = __popcll(bal);        // contiguous prefix in tile
    }
    // 512 tile ids, 2 per thread, coalesced
#pragma unroll
    for (int k = 0; k < 2; k++) {
        const int idx = tid + k * 256;
        const int i   = idx >> 5;       // c within tile (0..15)
        const int j   = idx & 31;
        const int sv  = srow[(size_t)i * NS + j0 + j];
        sids[i][j] = (sv >= VOCAB) ? UNK : sv;
    }
    __syncthreads();

    const int nnz = nnz_sh;

    // stage f32 query rows for valid j's (wave w -> rows w, w+4, ...)
    float4* qt4 = (float4*)qt;
    for (int r = wave; r < nnz; r += 4)
        qt4[r * 64 + lane] = emb4[(size_t)qids[r] * (EMBED / 4) + lane];
    __syncthreads();

    float acc[CTILE];
#pragma unroll
    for (int i = 0; i < CTILE; i++) acc[i] = 0.f;

    for (int j = wave; j < nnz; j += 4) {
        const float4 qv = qt4[j * 64 + lane];        // ds_read_b128
        uint2 a[CTILE];
#pragma unroll
        for (int i = 0; i < CTILE; i++)
            a[i] = bfe[(size_t)sids[i][j] * 64 + lane];   // 8 B/lane bf16 gather
#pragma unroll
        for (int i = 0; i < CTILE; i++) {
            const float f0 = __uint_as_float(a[i].x << 16);
            const float f1 = __uint_as_float(a[i].x & 0xffff0000u);
            const float f2 = __uint_as_float(a[i].y << 16);
            const float f3 = __uint_as_float(a[i].y & 0xffff0000u);
            acc[i] += f0 * qv.x + f1 * qv.y + f2 * qv.z + f3 * qv.w;
        }
    }

#pragma unroll
    for (int off = 32; off > 0; off >>= 1)
#pragma unroll
        for (int i = 0; i < CTILE; i++)
            acc[i] += __shfl_down(acc[i], off, 64);

    __shared__ float red[4][CTILE];
    if (lane == 0)
#pragma unroll
        for (int i = 0; i < CTILE; i++) red[wave][i] = acc[i];
    __syncthreads();

    if (tid < CTILE) {
        const float s = red[0][tid] + red[1][tid] + red[2][tid] + red[3][tid];
        partial[(size_t)jt * (NB * NC) + b * NC + c0 + tid] = s;
    }
}

// ---- f32 fallback (proven R5 path), JT=8/JLEN=64, CTILE=8 ----
__global__ __launch_bounds__(256) void scores_f32_kernel(
    const int* __restrict__ src, const int* __restrict__ q,
    const float* __restrict__ emb, float* __restrict__ partial)
{
    const int x  = blockIdx.x;
    const int jt = x & 7;
    const int ct = (x >> 3) & 7;
    const int b  = x >> 6;
    const int c0 = ct * 8;
    const int j0 = jt * 64;

    const int tid = threadIdx.x, wave = tid >> 6, lane = tid & 63;
    const float4* __restrict__ emb4 = (const float4*)emb;
    const int* __restrict__ qrow = q + (size_t)b * NS;
    const int* __restrict__ srow = src + ((size_t)b * NC + c0) * NS;

    float acc[8];
#pragma unroll
    for (int i = 0; i < 8; i++) acc[i] = 0.f;

    for (int j = j0 + wave; j < j0 + 64; j += 4) {
        const int qv = qrow[j];
        if (qv > 0) {
            const int qid = (qv >= VOCAB) ? UNK : qv;
            const float4 eq = emb4[(size_t)qid * (EMBED / 4) + lane];
            float4 a[8];
#pragma unroll
            for (int i = 0; i < 8; i++) {
                const int sv = srow[(size_t)i * NS + j];
                a[i] = emb4[(size_t)((sv >= VOCAB) ? UNK : sv) * (EMBED / 4) + lane];
            }
#pragma unroll
            for (int i = 0; i < 8; i++)
                acc[i] += a[i].x * eq.x + a[i].y * eq.y + a[i].z * eq.z + a[i].w * eq.w;
        }
    }
#pragma unroll
    for (int off = 32; off > 0; off >>= 1)
#pragma unroll
        for (int i = 0; i < 8; i++)
            acc[i] += __shfl_down(acc[i], off, 64);

    __shared__ float red[4][8];
    if (lane == 0)
#pragma unroll
        for (int i = 0; i < 8; i++) red[wave][i] = acc[i];
    __syncthreads();
    if (tid < 8)
        partial[(size_t)jt * (NB * NC) + b * NC + c0 + tid] =
            red[0][tid] + red[1][tid] + red[2][tid] + red[3][tid];
}

// One block per b. Wave 0: sum jtn partials -> softmax -> sims + argmax;
// then all 256 threads copy the winning source row as f32.
__global__ __launch_bounds__(256) void finalize_kernel(
    const float* __restrict__ partial, const int* __restrict__ src,
    float* __restrict__ out, int jtn)
{
    const int b = blockIdx.x, tid = threadIdx.x;
    __shared__ int top_sh;

    if (tid < 64) {
        float s = 0.f;
        for (int t = 0; t < jtn; t++)
            s += partial[(size_t)t * (NB * NC) + b * NC + tid];

        float m = s;
#pragma unroll
        for (int off = 32; off > 0; off >>= 1)
            m = fmaxf(m, __shfl_xor(m, off, 64));
        const float e = expf(s - m);
        float sum = e;
#pragma unroll
        for (int off = 32; off > 0; off >>= 1)
            sum += __shfl_xor(sum, off, 64);

        out[NB * NS + b * NC + tid] = e / sum;       // sims after 8192 ids

        const unsigned long long ballot = __ballot(s == m);
        if (tid == 0) top_sh = __ffsll(ballot) - 1;  // first occurrence
    }
    __syncthreads();

    const int top = top_sh;
    const int* __restrict__ srow = src + ((size_t)b * NC + top) * NS;
    for (int j = tid; j < NS; j += 256)
        out[b * NS + j] = (float)srow[j];
}

extern "C" void kernel_launch(void* const* d_in, const int* in_sizes, int n_in,
                              void* d_out, int out_size, void* d_ws, size_t ws_size,
                              hipStream_t stream) {
    const int*   src = (const int*)d_in[0];    // [NB*NC, NS] int32
    const int*   q   = (const int*)d_in[1];    // [NB, NS] int32
    const float* emb = (const float*)d_in[3];  // [VOCAB, EMBED] f32
    float* out = (float*)d_out;                // 8192 out_sources + 1024 sims (f32)

    if (ws_size >= BF_TABLE_BYTES + PARTIAL_ELEMS * sizeof(float)) {
        unsigned int* bf = (unsigned int*)d_ws;
        float* partial = (float*)((char*)d_ws + BF_TABLE_BYTES);
        convert_kernel<<<VOCAB * EMBED / 2048, 256, 0, stream>>>(emb, bf);
        scores_bf_kernel<<<NB * (NC / CTILE) * JT, 256, 0, stream>>>(src, q, emb, bf, partial);
        finalize_kernel<<<NB, 256, 0, stream>>>(partial, src, out, JT);
    } else {
        float* partial = (float*)d_ws;         // 8192 floats
        scores_f32_kernel<<<NB * 8 * 8, 256, 0, stream>>>(src, q, emb, partial);
        finalize_kernel<<<NB, 256, 0, stream>>>(partial, src, out, 8);
    }
}